// Round 16
// baseline (1280.689 us; speedup 1.0000x reference)
//
#include <hip/hip_runtime.h>
#include <math.h>

// Dims (fixed per reference)
#define B   128
#define L   50
#define V   100000
#define ND  4
#define D   64

// out layout: P_v (B*V) | infomax_loss (1) | gnn (B*ND*L*D)

__device__ __forceinline__ float log_sigmoid(float x) {
    if (x >= 0.f) return -log1pf(expf(-x));
    return x - log1pf(expf(x));
}

// K0: gnn broadcast-write, full-GPU wide. One float4 per thread.
__global__ __launch_bounds__(256) void k0_gnn(
    const int* __restrict__ nodes, const float* __restrict__ emb_i,
    float* __restrict__ gnn)
{
    const int idx = blockIdx.x * 256 + threadIdx.x;   // float4 index
    const int d4   = idx & (D / 4 - 1);               // 0..15
    const int rest = idx >> 4;                        // b*ND*L + n*L + l
    const int l    = rest % L;
    const int bn   = rest / L;
    const int b    = bn >> 2;
    const int node = nodes[b * L + l];
    const float4 val = reinterpret_cast<const float4*>(emb_i)[node * (D / 4) + d4];
    reinterpret_cast<float4*>(gnn)[idx] = val;
}

// K1: per-b (1 wave, t == d): masked-mean gr, last row, u = W_im@gr,
// h = tanh([gr|last]@W_pvsd + b). Also zero-inits loss.
__global__ __launch_bounds__(64) void k1_small(
    const int* __restrict__ nodes, const int* __restrict__ mask,
    const int* __restrict__ sli, const float* __restrict__ emb_i,
    const float* __restrict__ W_pvsd, const float* __restrict__ b_pvsd,
    const float* __restrict__ W_im,
    float* __restrict__ u, float* __restrict__ h, float* __restrict__ loss)
{
    const int b = blockIdx.x;
    const int t = threadIdx.x;     // = d
    if (b == 0 && t == 0) loss[0] = 0.f;
    __shared__ int   s_nodes[L];
    __shared__ float s_mask[L];
    __shared__ float s_gr[D], s_last[D];
    if (t < L) {
        s_nodes[t] = nodes[b * L + t];
        s_mask[t]  = (float)mask[b * L + t];
    }
    __syncthreads();
    float msum = 0.f, acc = 0.f;
    for (int l = 0; l < L; ++l) {
        float m = s_mask[l];
        msum += m;
        acc  += m * emb_i[(size_t)s_nodes[l] * D + t];
    }
    s_gr[t]   = acc / msum;
    s_last[t] = emb_i[(size_t)s_nodes[sli[b]] * D + t];
    __syncthreads();
    float uu = 0.f;
    #pragma unroll
    for (int e = 0; e < D; ++e) uu += W_im[t * D + e] * s_gr[e];
    u[b * D + t] = uu;
    float pre = b_pvsd[t];
    #pragma unroll
    for (int k = 0; k < D; ++k) pre += s_gr[k]   * W_pvsd[k * D + t];
    #pragma unroll
    for (int k = 0; k < D; ++k) pre += s_last[k] * W_pvsd[(D + k) * D + t];
    h[b * D + t] = tanhf(pre);
}

// K3: infomax partials per b, accumulated into the scalar loss.
__global__ __launch_bounds__(64) void k3_infomax(
    const float* __restrict__ u, const float* __restrict__ gnn,
    float* __restrict__ loss)
{
    const int b = blockIdx.x;
    const int t = threadIdx.x;
    __shared__ float s_up[D], s_un[D];
    const int bm1 = (b + B - 1) % B;
    s_up[t] = u[b * D + t];
    s_un[t] = u[bm1 * D + t];
    __syncthreads();
    float lsp = 0.f, lsn = 0.f;
    if (t < L) {
        const float* se = gnn + ((size_t)(b * ND) * L + t) * D;  // n=0 copy
        float sp = 0.f, sn = 0.f;
        #pragma unroll
        for (int d2 = 0; d2 < D; ++d2) {
            float vv = se[d2];
            sp += vv * s_up[d2];
            sn += vv * s_un[d2];
        }
        lsp = log_sigmoid(sp);
        lsn = log_sigmoid(-sn);
    }
    float tot = lsp + lsn;
    for (int off = 32; off > 0; off >>= 1) tot += __shfl_down(tot, off);
    if (t == 0) atomicAdd(loss, -tot / (float)(B * L));
}

// K5: P_v[b,v] = h[b] . emb_i[v]
// R15 post-mortem: the invariant ~51us floor across R9-R15 is the inner-
// loop h-loads: wave-uniform s_load_dwordx4 thrash the scalar K$ (every CU
// hosts all 8 b-slices = 32KB working set) -> chronic ~200cy L2 round
// trips that ~3 waves/SIMD can't hide. VT=2 (R15) made the dependent fma
// bursts longer and halved wave count -> 91us, confirming latency-bound.
// Fix: stage the block's h-slice in LDS (8KB, one cooperative copy), read
// via ds_read_b128 at wave-uniform addresses (broadcast, conflict-free,
// lgkmcnt-pipelined). NBSPLIT=4 halves FETCH to ~51MB. launch_bounds(256,2)
// gives a 128-VGPR budget so the allocator never re-sinks the E-line loads
// (R4/R5 pathology; acc 32 + line 16 + transient ~24 = ~75 VGPR).
#define NBSPLIT 4
#define NB (B / NBSPLIT)   // 32 b per thread
#define PIN16(p,q,r,s) asm volatile("" : \
    "+v"(p.x), "+v"(p.y), "+v"(p.z), "+v"(p.w), \
    "+v"(q.x), "+v"(q.y), "+v"(q.z), "+v"(q.w), \
    "+v"(r.x), "+v"(r.y), "+v"(r.z), "+v"(r.w), \
    "+v"(s.x), "+v"(s.y), "+v"(s.z), "+v"(s.w))

__global__ __launch_bounds__(256, 2) void k5_pv(
    const float* __restrict__ h, const float* __restrict__ emb_i,
    float* __restrict__ pv)
{
    const int bx = blockIdx.x >> 2;
    const int by = blockIdx.x & 3;
    const int v  = bx * 256 + threadIdx.x;
    const int b0 = by * NB;
    const bool active = (v < V);
    const int vc = active ? v : (V - 1);
    const float4* r4 = reinterpret_cast<const float4*>(emb_i + (size_t)vc * D);

    // Stage h[b0..b0+NB-1][0..63] into LDS: NB*16 float4 = 512 quads, 8KB.
    __shared__ float4 sh[NB * (D / 4)];
    {
        const float4* hg = reinterpret_cast<const float4*>(h) + (size_t)b0 * (D / 4);
        const int t = threadIdx.x;
        sh[t]       = hg[t];
        sh[t + 256] = hg[t + 256];
    }
    __syncthreads();

    float acc[NB];
    #pragma unroll
    for (int j = 0; j < NB; ++j) acc[j] = 0.f;

    #pragma unroll
    for (int KB = 0; KB < 4; ++KB) {
        // one 64B line of this thread's emb row, consumed completely below
        float4 q0 = r4[4 * KB + 0];
        float4 q1 = r4[4 * KB + 1];
        float4 q2 = r4[4 * KB + 2];
        float4 q3 = r4[4 * KB + 3];
        PIN16(q0, q1, q2, q3);   // line resident; nothing to sink into j-loop
        #pragma unroll
        for (int j = 0; j < NB; ++j) {
            const float4* hj = &sh[j * (D / 4) + 4 * KB];  // uniform -> ds_read broadcast
            float4 h0 = hj[0], h1 = hj[1], h2 = hj[2], h3 = hj[3];
            float a = acc[j];
            a = fmaf(q0.x, h0.x, a); a = fmaf(q0.y, h0.y, a);
            a = fmaf(q0.z, h0.z, a); a = fmaf(q0.w, h0.w, a);
            a = fmaf(q1.x, h1.x, a); a = fmaf(q1.y, h1.y, a);
            a = fmaf(q1.z, h1.z, a); a = fmaf(q1.w, h1.w, a);
            a = fmaf(q2.x, h2.x, a); a = fmaf(q2.y, h2.y, a);
            a = fmaf(q2.z, h2.z, a); a = fmaf(q2.w, h2.w, a);
            a = fmaf(q3.x, h3.x, a); a = fmaf(q3.y, h3.y, a);
            a = fmaf(q3.z, h3.z, a); a = fmaf(q3.w, h3.w, a);
            acc[j] = a;
        }
    }

    if (active) {
        #pragma unroll
        for (int j = 0; j < NB; ++j)
            pv[(size_t)(b0 + j) * V + v] = acc[j];
    }
}

extern "C" void kernel_launch(void* const* d_in, const int* in_sizes, int n_in,
                              void* d_out, int out_size, void* d_ws, size_t ws_size,
                              hipStream_t stream)
{
    const int*   nodes  = (const int*)d_in[0];
    const int*   sli    = (const int*)d_in[4];
    const int*   mask   = (const int*)d_in[6];
    const float* emb_i  = (const float*)d_in[7];
    const float* W_pvsd = (const float*)d_in[13];
    const float* b_pvsd = (const float*)d_in[14];
    const float* W_im   = (const float*)d_in[15];

    float* pv   = (float*)d_out;               // B*V
    float* loss = pv + (size_t)B * V;          // 1
    float* gnn  = loss + 1;                    // B*ND*L*D

    float* ws = (float*)d_ws;
    float* u  = ws;                            // B*D
    float* h  = u + B * D;                     // B*D

    k0_gnn<<<(B * ND * L * (D / 4)) / 256, 256, 0, stream>>>(nodes, emb_i, gnn);
    k1_small<<<B, 64, 0, stream>>>(nodes, mask, sli, emb_i, W_pvsd, b_pvsd,
                                   W_im, u, h, loss);
    k3_infomax<<<B, 64, 0, stream>>>(u, gnn, loss);
    k5_pv<<<((V + 255) / 256) * NBSPLIT, 256, 0, stream>>>(h, emb_i, pv);
}

// Round 17
// 57.051 us; speedup vs baseline: 22.4480x; 22.4480x over previous
//
#include <hip/hip_runtime.h>
#include <math.h>

// Dims (fixed per reference)
#define B   128
#define L   50
#define V   100000
#define ND  4
#define D   64

// out layout: P_v (B*V) | infomax_loss (1) | gnn (B*ND*L*D)

typedef __attribute__((ext_vector_type(8))) short s8v;   // 8 bf16 (4 VGPR)
typedef __attribute__((ext_vector_type(4))) float f4v;   // MFMA acc

__device__ __forceinline__ float log_sigmoid(float x) {
    if (x >= 0.f) return -log1pf(expf(-x));
    return x - log1pf(expf(x));
}

// bf16 round-to-nearest-even helpers (bit ops, no header dependency)
__device__ __forceinline__ short bf16rne(float x) {
    unsigned u = __float_as_uint(x);
    unsigned r = u + 0x7FFFu + ((u >> 16) & 1u);
    return (short)(r >> 16);
}
__device__ __forceinline__ float bf16f(short s) {
    return __uint_as_float(((unsigned)(unsigned short)s) << 16);
}

// K0: gnn broadcast-write, full-GPU wide. One float4 per thread.
__global__ __launch_bounds__(256) void k0_gnn(
    const int* __restrict__ nodes, const float* __restrict__ emb_i,
    float* __restrict__ gnn)
{
    const int idx = blockIdx.x * 256 + threadIdx.x;   // float4 index
    const int d4   = idx & (D / 4 - 1);               // 0..15
    const int rest = idx >> 4;                        // b*ND*L + n*L + l
    const int l    = rest % L;
    const int bn   = rest / L;
    const int b    = bn >> 2;
    const int node = nodes[b * L + l];
    const float4 val = reinterpret_cast<const float4*>(emb_i)[node * (D / 4) + d4];
    reinterpret_cast<float4*>(gnn)[idx] = val;
}

// K1: per-b (1 wave, t == d): masked-mean gr, last row, u = W_im@gr,
// h = tanh([gr|last]@W_pvsd + b). Writes h as bf16 hi/lo pair for the MFMA
// GEMM (k5). Also zero-inits loss.
__global__ __launch_bounds__(64) void k1_small(
    const int* __restrict__ nodes, const int* __restrict__ mask,
    const int* __restrict__ sli, const float* __restrict__ emb_i,
    const float* __restrict__ W_pvsd, const float* __restrict__ b_pvsd,
    const float* __restrict__ W_im,
    float* __restrict__ u, short* __restrict__ hh, short* __restrict__ hl,
    float* __restrict__ loss)
{
    const int b = blockIdx.x;
    const int t = threadIdx.x;     // = d
    if (b == 0 && t == 0) loss[0] = 0.f;
    __shared__ int   s_nodes[L];
    __shared__ float s_mask[L];
    __shared__ float s_gr[D], s_last[D];
    if (t < L) {
        s_nodes[t] = nodes[b * L + t];
        s_mask[t]  = (float)mask[b * L + t];
    }
    __syncthreads();
    float msum = 0.f, acc = 0.f;
    for (int l = 0; l < L; ++l) {
        float m = s_mask[l];
        msum += m;
        acc  += m * emb_i[(size_t)s_nodes[l] * D + t];
    }
    s_gr[t]   = acc / msum;
    s_last[t] = emb_i[(size_t)s_nodes[sli[b]] * D + t];
    __syncthreads();
    float uu = 0.f;
    #pragma unroll
    for (int e = 0; e < D; ++e) uu += W_im[t * D + e] * s_gr[e];
    u[b * D + t] = uu;
    float pre = b_pvsd[t];
    #pragma unroll
    for (int k = 0; k < D; ++k) pre += s_gr[k]   * W_pvsd[k * D + t];
    #pragma unroll
    for (int k = 0; k < D; ++k) pre += s_last[k] * W_pvsd[(D + k) * D + t];
    float hv = tanhf(pre);
    short hi = bf16rne(hv);
    short lo = bf16rne(hv - bf16f(hi));
    hh[b * D + t] = hi;
    hl[b * D + t] = lo;
}

// K3: infomax partials per b, accumulated into the scalar loss.
__global__ __launch_bounds__(64) void k3_infomax(
    const float* __restrict__ u, const float* __restrict__ gnn,
    float* __restrict__ loss)
{
    const int b = blockIdx.x;
    const int t = threadIdx.x;
    __shared__ float s_up[D], s_un[D];
    const int bm1 = (b + B - 1) % B;
    s_up[t] = u[b * D + t];
    s_un[t] = u[bm1 * D + t];
    __syncthreads();
    float lsp = 0.f, lsn = 0.f;
    if (t < L) {
        const float* se = gnn + ((size_t)(b * ND) * L + t) * D;  // n=0 copy
        float sp = 0.f, sn = 0.f;
        #pragma unroll
        for (int d2 = 0; d2 < D; ++d2) {
            float vv = se[d2];
            sp += vv * s_up[d2];
            sn += vv * s_un[d2];
        }
        lsp = log_sigmoid(sp);
        lsn = log_sigmoid(-sn);
    }
    float tot = lsp + lsn;
    for (int off = 32; off > 0; off >>= 1) tot += __shfl_down(tot, off);
    if (t == 0) atomicAdd(loss, -tot / (float)(B * L));
}

// K5: P_v = h(128x64) @ emb^T via bf16-split MFMA (R16 post-mortem: every
// scalar/vector variant hit a ~51us h-broadcast latency floor — K$ thrash,
// L1 thrash, or LDS issue rate. The matrix core broadcasts the B-operand in
// hardware). fp32 = bf16_hi + bf16_lo; 4 cross-product MFMAs accumulate in
// fp32 -> ~1e-6 error, negligible vs the existing 3.05e-5 absmax.
// Fragment recipe per HW-verified m89/m97: A and B both loaded as
// [free = lane&15][k = 8*(lane>>4)+i] (consistent k-bijection cancels);
// C/D: row = 4*(lane>>4)+reg, col = lane&15. col -> v gives coalesced
// 64B store segments. Wave = 16-v tile x all 128 b: 8 C tiles, 64 MFMA,
// h (32KB bf16 hi+lo) is L2-resident. One f4 acc live at a time -> ~50
// VGPR, no LDS, no spill surface.
__global__ __launch_bounds__(256) void k5_mfma(
    const short* __restrict__ hh, const short* __restrict__ hl,
    const float* __restrict__ emb_i, float* __restrict__ pv)
{
    const int lane = threadIdx.x & 63;
    const int wid  = threadIdx.x >> 6;
    const int lm   = lane & 15;
    const int lg   = lane >> 4;
    const int v0   = (blockIdx.x * 4 + wid) * 16;
    const int vcol = v0 + lm;
    const int vld  = vcol < V ? vcol : (V - 1);

    // emb row chunk for this lane: k = 8*lg + i (kk=0) and +32 (kk=1)
    const float* ep = emb_i + (size_t)vld * D + 8 * lg;
    f4v ea = *(const f4v*)(ep);
    f4v eb = *(const f4v*)(ep + 4);
    f4v ec = *(const f4v*)(ep + 32);
    f4v ed = *(const f4v*)(ep + 36);

    s8v ehi0, elo0, ehi1, elo1;
    #pragma unroll
    for (int i = 0; i < 4; ++i) {
        { float x = ea[i]; short h = bf16rne(x); ehi0[i]     = h; elo0[i]     = bf16rne(x - bf16f(h)); }
        { float x = eb[i]; short h = bf16rne(x); ehi0[i + 4] = h; elo0[i + 4] = bf16rne(x - bf16f(h)); }
        { float x = ec[i]; short h = bf16rne(x); ehi1[i]     = h; elo1[i]     = bf16rne(x - bf16f(h)); }
        { float x = ed[i]; short h = bf16rne(x); ehi1[i + 4] = h; elo1[i + 4] = bf16rne(x - bf16f(h)); }
    }

    #pragma unroll
    for (int bt = 0; bt < 8; ++bt) {
        const int b = 16 * bt + lm;                    // A free dim = lane&15
        const short* hb = hh + b * D + 8 * lg;
        const short* lb = hl + b * D + 8 * lg;
        s8v ah0 = *(const s8v*)(hb);
        s8v ah1 = *(const s8v*)(hb + 32);
        s8v al0 = *(const s8v*)(lb);
        s8v al1 = *(const s8v*)(lb + 32);
        f4v c = {0.f, 0.f, 0.f, 0.f};
        c = __builtin_amdgcn_mfma_f32_16x16x32_bf16(ah0, ehi0, c, 0, 0, 0);
        c = __builtin_amdgcn_mfma_f32_16x16x32_bf16(ah1, ehi1, c, 0, 0, 0);
        c = __builtin_amdgcn_mfma_f32_16x16x32_bf16(ah0, elo0, c, 0, 0, 0);
        c = __builtin_amdgcn_mfma_f32_16x16x32_bf16(ah1, elo1, c, 0, 0, 0);
        c = __builtin_amdgcn_mfma_f32_16x16x32_bf16(al0, ehi0, c, 0, 0, 0);
        c = __builtin_amdgcn_mfma_f32_16x16x32_bf16(al1, ehi1, c, 0, 0, 0);
        c = __builtin_amdgcn_mfma_f32_16x16x32_bf16(al0, elo0, c, 0, 0, 0);
        c = __builtin_amdgcn_mfma_f32_16x16x32_bf16(al1, elo1, c, 0, 0, 0);
        if (vcol < V) {
            const int br = 16 * bt + 4 * lg;           // C row = 4*lg + reg
            pv[(size_t)(br + 0) * V + vcol] = c[0];
            pv[(size_t)(br + 1) * V + vcol] = c[1];
            pv[(size_t)(br + 2) * V + vcol] = c[2];
            pv[(size_t)(br + 3) * V + vcol] = c[3];
        }
    }
}

extern "C" void kernel_launch(void* const* d_in, const int* in_sizes, int n_in,
                              void* d_out, int out_size, void* d_ws, size_t ws_size,
                              hipStream_t stream)
{
    const int*   nodes  = (const int*)d_in[0];
    const int*   sli    = (const int*)d_in[4];
    const int*   mask   = (const int*)d_in[6];
    const float* emb_i  = (const float*)d_in[7];
    const float* W_pvsd = (const float*)d_in[13];
    const float* b_pvsd = (const float*)d_in[14];
    const float* W_im   = (const float*)d_in[15];

    float* pv   = (float*)d_out;               // B*V
    float* loss = pv + (size_t)B * V;          // 1
    float* gnn  = loss + 1;                    // B*ND*L*D

    float* ws = (float*)d_ws;
    float* u  = ws;                            // B*D floats
    short* hh = (short*)(u + B * D);           // B*D bf16 hi
    short* hl = hh + B * D;                    // B*D bf16 lo

    k0_gnn<<<(B * ND * L * (D / 4)) / 256, 256, 0, stream>>>(nodes, emb_i, gnn);
    k1_small<<<B, 64, 0, stream>>>(nodes, mask, sli, emb_i, W_pvsd, b_pvsd,
                                   W_im, u, hh, hl, loss);
    k3_infomax<<<B, 64, 0, stream>>>(u, gnn, loss);
    // V/16 = 6250 v-tiles, 4 per block (one per wave)
    k5_mfma<<<(V / 16 + 3) / 4, 256, 0, stream>>>(hh, hl, emb_i, pv);
}